// Round 1
// baseline (92.084 us; speedup 1.0000x reference)
//
#include <hip/hip_runtime.h>

typedef unsigned short u16;
typedef __attribute__((ext_vector_type(8))) short short8;
typedef __attribute__((ext_vector_type(4))) float f32x4;

typedef void gvoid_t __attribute__((address_space(1)));
typedef void lvoid_t __attribute__((address_space(3)));

#define M_DIM 8192   // B*T
#define N_DIM 1024   // K codebook entries
#define K_DIM 512    // D

__device__ __forceinline__ void async_copy16(const void* g, void* l) {
  // lane i's 16B land at (wave-uniform l) + i*16.
  __builtin_amdgcn_global_load_lds((gvoid_t*)g, (lvoid_t*)l, 16, 0, 0);
}

__device__ __forceinline__ unsigned bf16bits(float v) {
  union { float f; unsigned u; } c; c.f = v;
  return (c.u + 0x7FFFu + ((c.u >> 16) & 1u)) >> 16;  // RNE
}

// Pass 1: fp32 -> bf16 convert + per-row sum of squares. One wave per row.
// Coalesced: lane i loads float4[lane] and float4[lane+64].
// NOTE (R5 post-mortem): fusing this into the GEMM regressed 91.2->94.2 us —
// fp32 A-loads + VALU cvt + ds_write on the K-loop critical path beat the
// async global_load_lds DMA path. Keep the two-pass structure.
__global__ __launch_bounds__(256) void cvt_sq_kernel(
    const float* __restrict__ x, const float* __restrict__ cb,
    u16* __restrict__ xb, u16* __restrict__ cbb,
    float* __restrict__ xsq, float* __restrict__ csq) {
  int row = blockIdx.x * 4 + (threadIdx.x >> 6);
  int lane = threadIdx.x & 63;
  const float* src; u16* dst; float* sq;
  if (row < M_DIM) {
    src = x + (size_t)row * K_DIM; dst = xb + (size_t)row * K_DIM; sq = xsq + row;
  } else {
    int r = row - M_DIM;
    src = cb + (size_t)r * K_DIM; dst = cbb + (size_t)r * K_DIM; sq = csq + r;
  }
  const float4* s4 = (const float4*)src;
  float4 v0 = s4[lane];
  float4 v1 = s4[lane + 64];
  float s = v0.x * v0.x + v0.y * v0.y + v0.z * v0.z + v0.w * v0.w +
            v1.x * v1.x + v1.y * v1.y + v1.z * v1.z + v1.w * v1.w;
  uint2* d2 = (uint2*)dst;
  d2[lane]      = make_uint2(bf16bits(v0.x) | (bf16bits(v0.y) << 16),
                             bf16bits(v0.z) | (bf16bits(v0.w) << 16));
  d2[lane + 64] = make_uint2(bf16bits(v1.x) | (bf16bits(v1.y) << 16),
                             bf16bits(v1.z) | (bf16bits(v1.w) << 16));
#pragma unroll
  for (int off = 32; off > 0; off >>= 1) s += __shfl_xor(s, off, 64);
  if (lane == 0) *sq = s;
}

// Pass 2: 128x128 MFMA GEMM (bf16, B^T layout) + distance epilogue.
// R6: deep-pipelined K-loop (T3/T4 counted-vmcnt + T5 setprio).
//   - 4 LDS buffers x BK=32 (4x16 KiB = 64 KiB, occupancy unchanged: 2 blk/CU)
//   - stage(s+2) issued at step s -> 2-step prefetch window
//   - s_waitcnt vmcnt(8) per step (stages s+1,s+2 stay in flight; no drain-to-0
//     in the main loop, unlike __syncthreads' vmcnt(0) lgkmcnt(0))
//   - ONE raw s_barrier per step. Write-hazard safe: stage(s+2) overwrites
//     buf[(s+2)&3], last read at step s-2; reads(s-2) complete before
//     barrier(s-1), and the stage issue is after barrier(s-1).
//   - s_setprio(1) around the MFMA cluster (T5).
// Kept from R3/R4: XOR bank swizzle (within 64B rows now: chunk ^ (row&3)),
// XCD-aware block mapping (per-XCD L2-resident working set), fragment layout,
// epilogue with nontemporal stores.
__global__ __launch_bounds__(256) void qgemm_kernel(
    const u16* __restrict__ A, const u16* __restrict__ B,
    const float* __restrict__ xsq, const float* __restrict__ csq,
    const float* __restrict__ prec, float* __restrict__ out) {
  __shared__ char lds[65536];  // buf b (b=0..3): A at b*16384, B at b*16384+8192
  const int tid = threadIdx.x;
  const int wave = tid >> 6, lane = tid & 63;

  const int lin = blockIdx.x;          // 0..511
  const int xcd = lin & 7;
  const int idx = lin >> 3;            // 0..63
  const int ytile = (xcd << 3) | (idx & 7);  // m-tile 0..63 (8 per XCD)
  const int xtile = idx >> 3;                // n-tile 0..7
  const int m0 = ytile * 128, n0 = xtile * 128;

  const int wm = wave >> 1, wn = wave & 1;   // 2x2 wave grid, 64x64 per wave
  const int ml = lane & 15, q = lane >> 4;

  // Staging geometry (BK=32): one 1KB chunk = 16 rows x 32 cols.
  // gload_lds writes lane's 16B at base + chunk*1024 + lane*16, i.e.
  // row = lane>>2, 16B-slot = lane&3. Pre-swizzle the GLOBAL k-chunk so that
  // slot p of row r holds global chunk p^(r&3) (involution, read applies same XOR).
  const int srow = lane >> 2;                 // row within 16-row chunk
  const int sc = (lane & 3) ^ (srow & 3);     // global 8-elem k-chunk for this slot
  const u16* gA0 = A + (size_t)(m0 + wave * 16 + srow) * K_DIM + sc * 8;
  const u16* gA1 = A + (size_t)(m0 + (wave + 4) * 16 + srow) * K_DIM + sc * 8;
  const u16* gB0 = B + (size_t)(n0 + wave * 16 + srow) * K_DIM + sc * 8;
  const u16* gB1 = B + (size_t)(n0 + (wave + 4) * 16 + srow) * K_DIM + sc * 8;

  auto stage = [&](int t) {  // stage K-step t (k = t*32) into buf t&3; 4 loads/wave
    char* base = lds + ((t & 3) << 14);
    const int ko = t * 32;
    async_copy16(gA0 + ko, base + wave * 1024);
    async_copy16(gA1 + ko, base + (wave + 4) * 1024);
    async_copy16(gB0 + ko, base + 8192 + wave * 1024);
    async_copy16(gB1 + ko, base + 8192 + (wave + 4) * 1024);
  };

  stage(0);
  stage(1);

  // Pre-load epilogue operands (drained by the first vmcnt; latency hidden).
  const float p = prec[0];
  float csv[4];
#pragma unroll
  for (int j = 0; j < 4; j++) csv[j] = csq[n0 + wn * 64 + j * 16 + ml];

  f32x4 acc[4][4] = {};
  const int pcol = ((q ^ (ml & 3)) << 4);  // swizzled 16B slot within 64B row

#pragma unroll
  for (int s = 0; s < 16; s++) {
    if (s < 14) {
      stage(s + 2);
      asm volatile("s_waitcnt vmcnt(8)" ::: "memory");  // stage(s) done; s+1,s+2 in flight
    } else if (s == 14) {
      asm volatile("s_waitcnt vmcnt(4)" ::: "memory");  // stage(14) done; 15 in flight
    } else {
      asm volatile("s_waitcnt vmcnt(0)" ::: "memory");  // stage(15) done
    }
    __builtin_amdgcn_s_barrier();  // all waves' stage(s) chunks visible

    const char* base = lds + ((s & 3) << 14);
    short8 a[4], b[4];
#pragma unroll
    for (int i = 0; i < 4; i++) {
      a[i] = *(const short8*)(base + (wm * 64 + i * 16 + ml) * 64 + pcol);
      b[i] = *(const short8*)(base + 8192 + (wn * 64 + i * 16 + ml) * 64 + pcol);
    }
    __builtin_amdgcn_s_setprio(1);
#pragma unroll
    for (int i = 0; i < 4; i++)
#pragma unroll
      for (int j = 0; j < 4; j++)
        acc[i][j] = __builtin_amdgcn_mfma_f32_16x16x32_bf16(a[i], b[j], acc[i][j], 0, 0, 0);
    __builtin_amdgcn_s_setprio(0);
    // No trailing barrier needed: buf[s&3] is next written by stage(s+4)-equiv
    // (i.e. stage(t) with t&3==s&3 is t=s+4), issued at step s+2, which is
    // after barrier(s+1) — and our reads completed before we reach it.
  }

  // Epilogue: out = p * (2*xc - ||x||^2 - ||c||^2)
  // C/D layout: col = lane&15, row = (lane>>4)*4 + reg  [m89-verified]
#pragma unroll
  for (int i = 0; i < 4; i++) {
#pragma unroll
    for (int r = 0; r < 4; r++) {
      int row = m0 + wm * 64 + i * 16 + q * 4 + r;
      float xs = xsq[row];
      float* orow = out + (size_t)row * N_DIM + n0 + wn * 64 + ml;
#pragma unroll
      for (int j = 0; j < 4; j++)
        __builtin_nontemporal_store(p * (2.0f * acc[i][j][r] - xs - csv[j]),
                                    orow + j * 16);
    }
  }
}

extern "C" void kernel_launch(void* const* d_in, const int* in_sizes, int n_in,
                              void* d_out, int out_size, void* d_ws, size_t ws_size,
                              hipStream_t stream) {
  const float* x    = (const float*)d_in[0];   // [8,1024,512] fp32
  const float* cb   = (const float*)d_in[1];   // [1024,512] fp32
  const float* prec = (const float*)d_in[2];   // [1] fp32
  float* out = (float*)d_out;                  // [8,1024,1024] fp32

  char* ws = (char*)d_ws;
  u16*   xb  = (u16*)(ws);                      // 8 MiB bf16 x
  u16*   cbb = (u16*)(ws + 8388608);            // 1 MiB bf16 codebook
  float* xsq = (float*)(ws + 9437184);          // 32 KiB
  float* csq = (float*)(ws + 9469952);          // 4 KiB

  cvt_sq_kernel<<<2304, 256, 0, stream>>>(x, cb, xb, cbb, xsq, csq);
  qgemm_kernel<<<512, 256, 0, stream>>>(xb, cbb, xsq, csq, prec, out);
}

// Round 2
// 91.099 us; speedup vs baseline: 1.0108x; 1.0108x over previous
//
#include <hip/hip_runtime.h>

typedef unsigned short u16;
typedef __attribute__((ext_vector_type(8))) short short8;
typedef __attribute__((ext_vector_type(4))) float f32x4;

typedef void gvoid_t __attribute__((address_space(1)));
typedef void lvoid_t __attribute__((address_space(3)));

#define M_DIM 8192   // B*T
#define N_DIM 1024   // K codebook entries
#define K_DIM 512    // D

__device__ __forceinline__ void async_copy16(const void* g, void* l) {
  // lane i's 16B land at (wave-uniform l) + i*16.
  __builtin_amdgcn_global_load_lds((gvoid_t*)g, (lvoid_t*)l, 16, 0, 0);
}

__device__ __forceinline__ unsigned bf16bits(float v) {
  union { float f; unsigned u; } c; c.f = v;
  return (c.u + 0x7FFFu + ((c.u >> 16) & 1u)) >> 16;  // RNE
}

// Pass 1: fp32 -> bf16 convert + per-row sum of squares. One wave per row.
// (R5 post-mortem: fusing into the GEMM regressed — keep two-pass.)
__global__ __launch_bounds__(256) void cvt_sq_kernel(
    const float* __restrict__ x, const float* __restrict__ cb,
    u16* __restrict__ xb, u16* __restrict__ cbb,
    float* __restrict__ xsq, float* __restrict__ csq) {
  int row = blockIdx.x * 4 + (threadIdx.x >> 6);
  int lane = threadIdx.x & 63;
  const float* src; u16* dst; float* sq;
  if (row < M_DIM) {
    src = x + (size_t)row * K_DIM; dst = xb + (size_t)row * K_DIM; sq = xsq + row;
  } else {
    int r = row - M_DIM;
    src = cb + (size_t)r * K_DIM; dst = cbb + (size_t)r * K_DIM; sq = csq + r;
  }
  const float4* s4 = (const float4*)src;
  float4 v0 = s4[lane];
  float4 v1 = s4[lane + 64];
  float s = v0.x * v0.x + v0.y * v0.y + v0.z * v0.z + v0.w * v0.w +
            v1.x * v1.x + v1.y * v1.y + v1.z * v1.z + v1.w * v1.w;
  uint2* d2 = (uint2*)dst;
  d2[lane]      = make_uint2(bf16bits(v0.x) | (bf16bits(v0.y) << 16),
                             bf16bits(v0.z) | (bf16bits(v0.w) << 16));
  d2[lane + 64] = make_uint2(bf16bits(v1.x) | (bf16bits(v1.y) << 16),
                             bf16bits(v1.z) | (bf16bits(v1.w) << 16));
#pragma unroll
  for (int off = 32; off > 0; off >>= 1) s += __shfl_xor(s, off, 64);
  if (lane == 0) *sq = s;
}

// Pass 2: 128x128 MFMA GEMM + distance epilogue.
// R7: 8-wave fine-phase schedule (T3+T4+T5 port).
//   - 512 threads, 2x4 wave grid, 64x32 output per wave -> 4 waves/SIMD at
//     2 blocks/CU (vs 2 waves/SIMD before) at IDENTICAL staging traffic.
//   - 16 phases, one per K=32 slice; ring of 4 LDS slots (16 KB each, 64 KB).
//   - Per phase: {6 ds_read_b128 || issue stage(s+2) (2 gload_lds) ->
//     s_waitcnt vmcnt(2) -> s_barrier -> setprio(1) 8 MFMA setprio(0)}.
//     vmcnt(2) leaves slice s+2 in flight across the barrier; no drain-to-0
//     until the s=14 tail.
//   - Hazard: slot s&3 rewritten by stage(s+4) (issued in phase s+2); reads(s)
//     drain via lgkmcnt before MFMA(s), >= 2 barriers earlier. DMA writes of
//     stage(s+2) target slot (s+2)&3, disjoint from any slot readable by a
//     wave that is at most one barrier behind the issuer.
// Kept verified pieces: R6 ring staging swizzle (sc = (lane&3)^(srow&3),
// read pcol = (q ^ (ml&3))<<4 on 64B rows), XCD block mapping, m89 C/D
// layout, nontemporal epilogue.
__global__ __launch_bounds__(512, 4) void qgemm_kernel(
    const u16* __restrict__ A, const u16* __restrict__ B,
    const float* __restrict__ xsq, const float* __restrict__ csq,
    const float* __restrict__ prec, float* __restrict__ out) {
  __shared__ char lds[65536];  // slot t&3 at (t&3)*16384: A 8KB, B 8KB
  const int tid = threadIdx.x;
  const int wave = tid >> 6, lane = tid & 63;

  const int lin = blockIdx.x;          // 0..511
  const int xcd = lin & 7;
  const int idx = lin >> 3;            // 0..63
  const int ytile = (xcd << 3) | (idx & 7);  // m-tile 0..63 (8 per XCD)
  const int xtile = idx >> 3;                // n-tile 0..7
  const int m0 = ytile * 128, n0 = xtile * 128;

  const int wm = wave >> 2, wn = wave & 3;   // 2x4 wave grid, 64x32 per wave
  const int ml = lane & 15, q = lane >> 4;

  // Staging: slice = K=32 (64B rows). Chunk = 16 rows x 64B = 1KB; each wave
  // stages 1 A-chunk + 1 B-chunk per slice. gload_lds writes lane's 16B at
  // base + lane*16 -> row = lane>>2, slot = lane&3. Pre-swizzle global k-chunk:
  // slot p of row r holds global chunk p^(r&3) (involution; read applies same XOR).
  const int srow = lane >> 2;                 // row within 16-row chunk
  const int sc = (lane & 3) ^ (srow & 3);     // global 8-elem k-chunk for this slot
  const u16* gA = A + (size_t)(m0 + wave * 16 + srow) * K_DIM + sc * 8;
  const u16* gB = B + (size_t)(n0 + wave * 16 + srow) * K_DIM + sc * 8;

  auto stage = [&](int t) {  // stage slice t (k = t*32) into slot t&3; 2 loads/wave
    char* base = lds + ((t & 3) << 14);
    const int ko = t * 32;
    async_copy16(gA + ko, base + wave * 1024);
    async_copy16(gB + ko, base + 8192 + wave * 1024);
  };

  // Epilogue operands first, then drain so loop vmcnt gates count only stages.
  const float p = prec[0];
  float csv[2];
#pragma unroll
  for (int j = 0; j < 2; j++) csv[j] = csq[n0 + wn * 32 + j * 16 + ml];
  asm volatile("s_waitcnt vmcnt(0)" ::: "memory");

  stage(0);
  stage(1);

  f32x4 acc[4][2] = {};
  const int pcol = ((q ^ (ml & 3)) << 4);  // swizzled 16B slot within 64B row

  asm volatile("s_waitcnt vmcnt(2)" ::: "memory");  // own stage(0) done
  __builtin_amdgcn_s_barrier();                     // all waves' stage(0) visible

#pragma unroll
  for (int s = 0; s < 16; s++) {
    const char* base = lds + ((s & 3) << 14);
    short8 a[4], b[2];
#pragma unroll
    for (int i = 0; i < 4; i++)
      a[i] = *(const short8*)(base + (wm * 64 + i * 16 + ml) * 64 + pcol);
#pragma unroll
    for (int j = 0; j < 2; j++)
      b[j] = *(const short8*)(base + 8192 + (wn * 32 + j * 16 + ml) * 64 + pcol);

    if (s < 14) {
      stage(s + 2);
      asm volatile("s_waitcnt vmcnt(2)" ::: "memory");  // stage(s+1) done; s+2 in flight
    } else if (s == 14) {
      asm volatile("s_waitcnt vmcnt(0)" ::: "memory");  // stage(15) done
    }
    __builtin_amdgcn_s_barrier();  // all waves' stage(s+1) chunks visible

    __builtin_amdgcn_s_setprio(1);
#pragma unroll
    for (int i = 0; i < 4; i++)
#pragma unroll
      for (int j = 0; j < 2; j++)
        acc[i][j] = __builtin_amdgcn_mfma_f32_16x16x32_bf16(a[i], b[j], acc[i][j], 0, 0, 0);
    __builtin_amdgcn_s_setprio(0);
  }

  // Epilogue: out = p * (2*xc - ||x||^2 - ||c||^2)
  // C/D layout: col = lane&15, row = (lane>>4)*4 + reg  [m89-verified]
#pragma unroll
  for (int i = 0; i < 4; i++) {
#pragma unroll
    for (int r = 0; r < 4; r++) {
      int row = m0 + wm * 64 + i * 16 + q * 4 + r;
      float xs = xsq[row];
      float* orow = out + (size_t)row * N_DIM + n0 + wn * 32 + ml;
#pragma unroll
      for (int j = 0; j < 2; j++)
        __builtin_nontemporal_store(p * (2.0f * acc[i][j][r] - xs - csv[j]),
                                    orow + j * 16);
    }
  }
}

extern "C" void kernel_launch(void* const* d_in, const int* in_sizes, int n_in,
                              void* d_out, int out_size, void* d_ws, size_t ws_size,
                              hipStream_t stream) {
  const float* x    = (const float*)d_in[0];   // [8,1024,512] fp32
  const float* cb   = (const float*)d_in[1];   // [1024,512] fp32
  const float* prec = (const float*)d_in[2];   // [1] fp32
  float* out = (float*)d_out;                  // [8,1024,1024] fp32

  char* ws = (char*)d_ws;
  u16*   xb  = (u16*)(ws);                      // 8 MiB bf16 x
  u16*   cbb = (u16*)(ws + 8388608);            // 1 MiB bf16 codebook
  float* xsq = (float*)(ws + 9437184);          // 32 KiB
  float* csq = (float*)(ws + 9469952);          // 4 KiB

  cvt_sq_kernel<<<2304, 256, 0, stream>>>(x, cb, xb, cbb, xsq, csq);
  qgemm_kernel<<<512, 512, 0, stream>>>(xb, cbb, xsq, csq, prec, out);
}